// Round 6
// baseline (62.334 us; speedup 1.0000x reference)
//
#include <hip/hip_runtime.h>
#include <cmath>

// ============================================================================
// DIAGNOSTIC ROUND: K2's tile loop is repeated REP=3 times (idempotent min/max
// mining -> bit-identical results) purely to inflate K2's dispatch duration
// above the harness's ~40us workspace-fill dispatches, so K2 finally appears
// in the rocprof top-5 with real counters. Next round reverts REP to 1.
// Base config = r0 (34.1us best): NSPLIT=8, partials tail, finalize_a/b.
// ============================================================================
#define REP 3

#define BN 8192
#define DIM 128
#define MARGIN_F 0.3f
#define NSPLIT 8            // column splits (1024 cols each)
#define CPS 1024
#define NT 8                // 128-col B tiles per panel
#define NPART (NSPLIT * 2)  // per-row partials: split x wc
#define FBLK 32
#define IMAX 0x7FFFFFFF
#define IMIN 0x80000000

typedef __attribute__((ext_vector_type(4))) int i32x4;

__device__ __forceinline__ int imin3(int a, int b, int c) { return min(a, min(b, c)); }
__device__ __forceinline__ int imax3(int a, int b, int c) { return max(a, max(b, c)); }

// ---------------- K1: fp32 row norms -> sqv + k-major i8 quantized copy ----------------
__global__ __launch_bounds__(256) void norm_cvt_k(
    const float* __restrict__ emb, float* __restrict__ sqv, unsigned short* __restrict__ EnQ16)
{
  int w = (blockIdx.x * blockDim.x + threadIdx.x) >> 6;  // one wave per row
  int lane = threadIdx.x & 63;
  if (w >= BN) return;
  float2 v = *reinterpret_cast<const float2*>(&emb[w * DIM + lane * 2]);
  float s = v.x * v.x + v.y * v.y;
  #pragma unroll
  for (int off = 32; off > 0; off >>= 1) s += __shfl_xor(s, off);
  float iv = 1.0f / fmaxf(sqrtf(s), 1e-12f);
  if (lane == 0) sqv[w] = s * iv * iv;
  int q0 = (int)rintf(127.0f * v.x * iv);
  int q1 = (int)rintf(127.0f * v.y * iv);
  unsigned short us = (unsigned short)((q0 & 255) | ((q1 & 255) << 8));
  int g = lane >> 3;                                  // k = 2*lane -> chunk g = lane/8
  EnQ16[(g * BN + w) * 8 + (lane & 7)] = us;
}

// ---------------- K2: fused i8-MFMA gram + hard mining (x REP for profiling) ----------------
__global__ __launch_bounds__(256, 2) void gram_mine_mfma_k(
    const char* __restrict__ EnQ, const int* __restrict__ lab,
    int* __restrict__ ap_part, int* __restrict__ an_part)
{
  __shared__ __align__(16) char Bs[2][16384];   // 2 x 16 KB

  const int tid = threadIdx.x;
  const int w = tid >> 6, l = tid & 63;
  const int wr = w >> 1, wc = w & 1;
  const int lrow = l & 15, lkg = l >> 4;

  const int rowBase = blockIdx.x * 128 + wr * 64;   // this wave's 64 rows
  const int panel   = blockIdx.y * CPS;

  // A fragments: 4 row-tiles x 2 K-steps (K=64 each), 16B per frag, coalesced
  i32x4 a[4][2];
  #pragma unroll
  for (int mi = 0; mi < 4; ++mi)
    #pragma unroll
    for (int kk = 0; kk < 2; ++kk)
      a[mi][kk] = *reinterpret_cast<const i32x4*>(
          EnQ + (((size_t)((kk << 2) + lkg) * BN + rowBase + mi * 16 + lrow) << 4));

  // byte-packed labels for the 16 rows this lane owns (labels < 128)
  unsigned rlbp[4];
  #pragma unroll
  for (int mi = 0; mi < 4; ++mi) {
    int rb = rowBase + mi * 16 + lkg * 4;
    rlbp[mi] = (unsigned)(lab[rb] & 255) | ((unsigned)(lab[rb + 1] & 255) << 8) |
               ((unsigned)(lab[rb + 2] & 255) << 16) | ((unsigned)(lab[rb + 3] & 255) << 24);
  }

  int ap[4][4], an[4][4];
  #pragma unroll
  for (int mi = 0; mi < 4; ++mi)
    #pragma unroll
    for (int r = 0; r < 4; ++r) { ap[mi][r] = IMAX; an[mi][r] = IMIN; }

  const i32x4 zf = {0, 0, 0, 0};   // shared zero C-operand: no per-half acc zero-init movs

  // async stage of one 128-col tile (1024 slots x 16B): wave w covers [w*256, w*256+256)
  auto stage = [&](int buf, int colTile) {
    #pragma unroll
    for (int i = 0; i < 4; ++i) {
      int s0 = (w << 8) + (i << 6);          // wave-uniform slot base
      int s  = s0 + l;
      const char* gp = EnQ + (((size_t)(s >> 7) * BN + colTile + (s & 127)) << 4);
      __builtin_amdgcn_global_load_lds(
          (const __attribute__((address_space(1))) void*)gp,
          (__attribute__((address_space(3))) void*)(&Bs[buf][s0 * 16]),
          16, 0, 0);
    }
  };

  #pragma unroll 1
  for (int rep = 0; rep < REP; ++rep) {
    // previous rep ends with __syncthreads() -> both buffers free to restage
    stage(0, panel);
    __syncthreads();   // drains vmcnt(0) then barrier

    int cur = 0;
    #pragma unroll 1
    for (int ct = 0; ct < NT; ++ct) {
      const int colTile = panel + ct * 128;
      const int colBase = colTile + wc * 64;

      if (ct + 1 < NT) stage(cur ^ 1, colTile + 128);   // in flight during compute

      // column labels for this wave's 64 cols
      int clb[4];
      #pragma unroll
      for (int ni = 0; ni < 4; ++ni) clb[ni] = lab[colBase + ni * 16 + lrow];

      const bool diag = (rowBase == colBase);

      #pragma unroll
      for (int half = 0; half < 2; ++half) {
        const int n0 = half * 2, n1 = half * 2 + 1;

        i32x4 acc[4][2];
        {  // kk = 0: C = zf (no zero-init of acc needed)
          i32x4 b[2];
          #pragma unroll
          for (int n = 0; n < 2; ++n)
            b[n] = *reinterpret_cast<const i32x4*>(
                &Bs[cur][((0 + lkg) * 128 + wc * 64 + (n0 + n) * 16 + lrow) * 16]);
          #pragma unroll
          for (int mi = 0; mi < 4; ++mi)
            #pragma unroll
            for (int n = 0; n < 2; ++n)
              acc[mi][n] = __builtin_amdgcn_mfma_i32_16x16x64_i8(
                  a[mi][0], b[n], zf, 0, 0, 0);
        }
        {  // kk = 1: chain
          i32x4 b[2];
          #pragma unroll
          for (int n = 0; n < 2; ++n)
            b[n] = *reinterpret_cast<const i32x4*>(
                &Bs[cur][((4 + lkg) * 128 + wc * 64 + (n0 + n) * 16 + lrow) * 16]);
          #pragma unroll
          for (int mi = 0; mi < 4; ++mi)
            #pragma unroll
            for (int n = 0; n < 2; ++n)
              acc[mi][n] = __builtin_amdgcn_mfma_i32_16x16x64_i8(
                  a[mi][1], b[n], acc[mi][n], 0, 0, 0);
        }

        // epilogue: mine integer dot; pairs feed v_min3_i32/v_max3_i32
        if (diag) {
          #pragma unroll
          for (int mi = 0; mi < 4; ++mi)
            #pragma unroll
            for (int r = 0; r < 4; ++r) {
              int rl = (int)((rlbp[mi] >> (r * 8)) & 255u);
              int rloc = mi * 16 + lkg * 4 + r;
              int d0 = acc[mi][0][r], d1 = acc[mi][1][r];
              bool s0 = (rl == clb[n0]), s1 = (rl == clb[n1]);
              bool e0 = (rloc == n0 * 16 + lrow), e1 = (rloc == n1 * 16 + lrow);
              int p0 = (s0 && !e0) ? d0 : IMAX;
              int p1 = (s1 && !e1) ? d1 : IMAX;
              int q0 = s0 ? IMIN : d0;
              int q1 = s1 ? IMIN : d1;
              ap[mi][r] = imin3(ap[mi][r], p0, p1);
              an[mi][r] = imax3(an[mi][r], q0, q1);
            }
        } else {
          #pragma unroll
          for (int mi = 0; mi < 4; ++mi)
            #pragma unroll
            for (int r = 0; r < 4; ++r) {
              int rl = (int)((rlbp[mi] >> (r * 8)) & 255u);
              int d0 = acc[mi][0][r], d1 = acc[mi][1][r];
              bool s0 = (rl == clb[n0]), s1 = (rl == clb[n1]);
              int p0 = s0 ? d0 : IMAX;
              int p1 = s1 ? d1 : IMAX;
              int q0 = s0 ? IMIN : d0;
              int q1 = s1 ? IMIN : d1;
              ap[mi][r] = imin3(ap[mi][r], p0, p1);
              an[mi][r] = imax3(an[mi][r], q0, q1);
            }
        }
      }

      __syncthreads();   // drains staging vmcnt + publishes buf^1, protects reuse
      cur ^= 1;
    }
  }

  // butterfly-reduce across the 16 lrow lanes sharing each C row, write partials
  const int part = blockIdx.y * 2 + wc;
  #pragma unroll
  for (int mi = 0; mi < 4; ++mi)
    #pragma unroll
    for (int r = 0; r < 4; ++r) {
      int p = ap[mi][r], n = an[mi][r];
      #pragma unroll
      for (int off = 1; off < 16; off <<= 1) {
        p = min(p, __shfl_xor(p, off));
        n = max(n, __shfl_xor(n, off));
      }
      if (lrow == 0) {
        int rg = rowBase + mi * 16 + lkg * 4 + r;
        ap_part[part * BN + rg] = p;
        an_part[part * BN + rg] = n;
      }
    }
}

// ---------------- K3a: per-row combine, d = sqrt(rs + 1 - 2*dot/127^2), margin ----------------
__global__ __launch_bounds__(256) void finalize_a_k(
    const int* __restrict__ ap_part, const int* __restrict__ an_part,
    const float* __restrict__ sqv,
    float* __restrict__ blk_sum, float* __restrict__ blk_cnt)
{
  int r = blockIdx.x * 256 + threadIdx.x;   // FBLK*256 == BN
  int apt = IMAX, ant = IMIN;               // min-idot pos / max-idot neg
  #pragma unroll 8
  for (int s = 0; s < NPART; ++s) {
    apt = min(apt, ap_part[s * BN + r]);
    ant = max(ant, an_part[s * BN + r]);
  }
  float sum = 0.f, cnt = 0.f;
  if (apt != IMAX && ant != IMIN) {
    const float sc = 2.0f / (127.0f * 127.0f);
    float rs1 = sqv[r] + 1.0f;
    float dap = sqrtf(fmaxf(fmaf(-sc, (float)apt, rs1), 0.f));
    float dan = sqrtf(fmaxf(fmaf(-sc, (float)ant, rs1), 0.f));
    sum = fmaxf(dap - dan + MARGIN_F, 0.f);
    cnt = 1.f;
  }
  #pragma unroll
  for (int off = 32; off > 0; off >>= 1) {
    sum += __shfl_xor(sum, off);
    cnt += __shfl_xor(cnt, off);
  }
  __shared__ float ssum[4], scnt[4];
  int wv = threadIdx.x >> 6;
  if ((threadIdx.x & 63) == 0) { ssum[wv] = sum; scnt[wv] = cnt; }
  __syncthreads();
  if (threadIdx.x == 0) {
    blk_sum[blockIdx.x] = ssum[0] + ssum[1] + ssum[2] + ssum[3];
    blk_cnt[blockIdx.x] = scnt[0] + scnt[1] + scnt[2] + scnt[3];
  }
}

// ---------------- K3b: final scalar ----------------
__global__ __launch_bounds__(64) void finalize_b_k(
    const float* __restrict__ blk_sum, const float* __restrict__ blk_cnt,
    float* __restrict__ out)
{
  int l = threadIdx.x;
  float s = (l < FBLK) ? blk_sum[l] : 0.f;
  float c = (l < FBLK) ? blk_cnt[l] : 0.f;
  #pragma unroll
  for (int off = 32; off > 0; off >>= 1) {
    s += __shfl_xor(s, off);
    c += __shfl_xor(c, off);
  }
  if (l == 0) out[0] = (c > 0.f) ? (s / c) : 0.f;
}

extern "C" void kernel_launch(void* const* d_in, const int* in_sizes, int n_in,
                              void* d_out, int out_size, void* d_ws, size_t ws_size,
                              hipStream_t stream)
{
  const float* emb = (const float*)d_in[0];
  const int*   lab = (const int*)d_in[1];
  float* out = (float*)d_out;
  float* ws  = (float*)d_ws;

  float* sqv     = ws;                          // BN floats
  int*   ap_part = (int*)(sqv + BN);            // NPART*BN ints
  int*   an_part = ap_part + NPART * BN;        // NPART*BN ints
  float* blk_sum = (float*)(an_part + NPART * BN);  // FBLK
  float* blk_cnt = blk_sum + FBLK;              // FBLK
  char*  EnQ     = (char*)(blk_cnt + FBLK);     // BN*DIM i8, k-major (~1 MB)

  norm_cvt_k<<<dim3(BN / 4), 256, 0, stream>>>(emb, sqv, (unsigned short*)EnQ);
  gram_mine_mfma_k<<<dim3(BN / 128, NSPLIT), 256, 0, stream>>>(EnQ, lab, ap_part, an_part);
  finalize_a_k<<<dim3(FBLK), 256, 0, stream>>>(ap_part, an_part, sqv, blk_sum, blk_cnt);
  finalize_b_k<<<dim3(1), 64, 0, stream>>>(blk_sum, blk_cnt, out);
}

// Round 7
// 33.462 us; speedup vs baseline: 1.8628x; 1.8628x over previous
//
#include <hip/hip_runtime.h>
#include <cmath>

#define BN 8192
#define DIM 128
#define MARGIN_F 0.3f
#define NSPLIT 8            // column splits (1024 cols each)
#define CPS 1024
#define NT 8                // 128-col B tiles per panel
#define NPART (NSPLIT * 2)  // per-row partials: split x wc
#define FBLK 32
#define IMAX 0x7FFFFFFF
#define IMIN 0x80000000

typedef __attribute__((ext_vector_type(4))) int i32x4;

__device__ __forceinline__ int imin3(int a, int b, int c) { return min(a, min(b, c)); }
__device__ __forceinline__ int imax3(int a, int b, int c) { return max(a, max(b, c)); }

// ---------------- K1: fp32 row norms -> sqv + k-major i8 quantized copy ----------------
__global__ __launch_bounds__(256) void norm_cvt_k(
    const float* __restrict__ emb, float* __restrict__ sqv, unsigned short* __restrict__ EnQ16)
{
  int w = (blockIdx.x * blockDim.x + threadIdx.x) >> 6;  // one wave per row
  int lane = threadIdx.x & 63;
  if (w >= BN) return;
  float2 v = *reinterpret_cast<const float2*>(&emb[w * DIM + lane * 2]);
  float s = v.x * v.x + v.y * v.y;
  #pragma unroll
  for (int off = 32; off > 0; off >>= 1) s += __shfl_xor(s, off);
  float iv = 1.0f / fmaxf(sqrtf(s), 1e-12f);
  if (lane == 0) sqv[w] = s * iv * iv;
  int q0 = (int)rintf(127.0f * v.x * iv);
  int q1 = (int)rintf(127.0f * v.y * iv);
  unsigned short us = (unsigned short)((q0 & 255) | ((q1 & 255) << 8));
  int g = lane >> 3;                                  // k = 2*lane -> chunk g = lane/8
  EnQ16[(g * BN + w) * 8 + (lane & 7)] = us;
}

// ---------------- K2: fused i8-MFMA gram + hard mining, half-deep pipelined ----------------
// r6 PMC (REP=3 steady state): MfmaUtil 15.7%, VALUBusy 48%, stalls ~36% -> the
// MFMA burst and the mining-VALU burst were phase-serialized. Restructure: two live
// half-accumulators; mining of the previous half is issued between/under the next
// half's MFMA chain so the VALU and MFMA pipes overlap. rl bytes pre-extracted
// (tile-invariant). ~170 VGPR total -> same 2 waves/SIMD tier, no spill ((256,2)).
__global__ __launch_bounds__(256, 2) void gram_mine_mfma_k(
    const char* __restrict__ EnQ, const int* __restrict__ lab,
    int* __restrict__ ap_part, int* __restrict__ an_part)
{
  __shared__ __align__(16) char Bs[2][16384];   // 2 x 16 KB

  const int tid = threadIdx.x;
  const int w = tid >> 6, l = tid & 63;
  const int wr = w >> 1, wc = w & 1;
  const int lrow = l & 15, lkg = l >> 4;

  const int rowBase = blockIdx.x * 128 + wr * 64;   // this wave's 64 rows
  const int panel   = blockIdx.y * CPS;

  // A fragments: 4 row-tiles x 2 K-steps (K=64 each), 16B per frag, coalesced
  i32x4 a[4][2];
  #pragma unroll
  for (int mi = 0; mi < 4; ++mi)
    #pragma unroll
    for (int kk = 0; kk < 2; ++kk)
      a[mi][kk] = *reinterpret_cast<const i32x4*>(
          EnQ + (((size_t)((kk << 2) + lkg) * BN + rowBase + mi * 16 + lrow) << 4));

  // row labels for the 16 rows this lane owns, pre-extracted (tile-invariant)
  int rlv[4][4];
  #pragma unroll
  for (int mi = 0; mi < 4; ++mi) {
    int rb = rowBase + mi * 16 + lkg * 4;
    #pragma unroll
    for (int r = 0; r < 4; ++r) rlv[mi][r] = lab[rb + r] & 255;
  }

  int ap[4][4], an[4][4];
  #pragma unroll
  for (int mi = 0; mi < 4; ++mi)
    #pragma unroll
    for (int r = 0; r < 4; ++r) { ap[mi][r] = IMAX; an[mi][r] = IMIN; }

  const i32x4 zf = {0, 0, 0, 0};   // shared zero C-operand

  // async stage of one 128-col tile (1024 slots x 16B): wave w covers [w*256, w*256+256)
  auto stage = [&](int buf, int colTile) {
    #pragma unroll
    for (int i = 0; i < 4; ++i) {
      int s0 = (w << 8) + (i << 6);          // wave-uniform slot base
      int s  = s0 + l;
      const char* gp = EnQ + (((size_t)(s >> 7) * BN + colTile + (s & 127)) << 4);
      __builtin_amdgcn_global_load_lds(
          (const __attribute__((address_space(1))) void*)gp,
          (__attribute__((address_space(3))) void*)(&Bs[buf][s0 * 16]),
          16, 0, 0);
    }
  };

  int cur = 0;

  // MFMA one 64x32 half (col subtiles n0, n0+1) of the current LDS tile into A
  auto halfMFMA = [&](i32x4 (&A)[4][2], int n0) {
    i32x4 b[2];
    #pragma unroll
    for (int n = 0; n < 2; ++n)
      b[n] = *reinterpret_cast<const i32x4*>(
          &Bs[cur][((0 + lkg) * 128 + wc * 64 + (n0 + n) * 16 + lrow) * 16]);
    #pragma unroll
    for (int mi = 0; mi < 4; ++mi)
      #pragma unroll
      for (int n = 0; n < 2; ++n)
        A[mi][n] = __builtin_amdgcn_mfma_i32_16x16x64_i8(a[mi][0], b[n], zf, 0, 0, 0);
    #pragma unroll
    for (int n = 0; n < 2; ++n)
      b[n] = *reinterpret_cast<const i32x4*>(
          &Bs[cur][((4 + lkg) * 128 + wc * 64 + (n0 + n) * 16 + lrow) * 16]);
    #pragma unroll
    for (int mi = 0; mi < 4; ++mi)
      #pragma unroll
      for (int n = 0; n < 2; ++n)
        A[mi][n] = __builtin_amdgcn_mfma_i32_16x16x64_i8(a[mi][1], b[n], A[mi][n], 0, 0, 0);
  };

  // mine one 64x32 half: l0/l1 = column labels of the two 16-col subtiles (per-lane),
  // c0/c1 = local column index of this lane in those subtiles (self-exclusion on diag)
  auto mineTile = [&](const i32x4 (&A)[4][2], int l0, int l1, int c0, int c1, bool dg) {
    if (!dg) {
      #pragma unroll
      for (int mi = 0; mi < 4; ++mi)
        #pragma unroll
        for (int r = 0; r < 4; ++r) {
          int d0 = A[mi][0][r], d1 = A[mi][1][r];
          bool s0 = (rlv[mi][r] == l0), s1 = (rlv[mi][r] == l1);
          int p0 = s0 ? d0 : IMAX;
          int p1 = s1 ? d1 : IMAX;
          int q0 = s0 ? IMIN : d0;
          int q1 = s1 ? IMIN : d1;
          ap[mi][r] = imin3(ap[mi][r], p0, p1);
          an[mi][r] = imax3(an[mi][r], q0, q1);
        }
    } else {
      #pragma unroll
      for (int mi = 0; mi < 4; ++mi)
        #pragma unroll
        for (int r = 0; r < 4; ++r) {
          int rloc = mi * 16 + lkg * 4 + r;
          int d0 = A[mi][0][r], d1 = A[mi][1][r];
          bool s0 = (rlv[mi][r] == l0), s1 = (rlv[mi][r] == l1);
          bool e0 = (rloc == c0), e1 = (rloc == c1);
          int p0 = (s0 && !e0) ? d0 : IMAX;
          int p1 = (s1 && !e1) ? d1 : IMAX;
          int q0 = s0 ? IMIN : d0;
          int q1 = s1 ? IMIN : d1;
          ap[mi][r] = imin3(ap[mi][r], p0, p1);
          an[mi][r] = imax3(an[mi][r], q0, q1);
        }
    }
  };

  stage(0, panel);
  __syncthreads();   // drains vmcnt(0) then barrier

  i32x4 accA[4][2], accB[4][2];
  int clb[4], clbP[4] = {0, 0, 0, 0};
  bool diagP = false;

  #pragma unroll 1
  for (int ct = 0; ct < NT; ++ct) {
    const int colTile = panel + ct * 128;
    const int colBase = colTile + wc * 64;

    if (ct + 1 < NT) stage(cur ^ 1, colTile + 128);   // in flight during compute

    #pragma unroll
    for (int ni = 0; ni < 4; ++ni) clb[ni] = lab[colBase + ni * 16 + lrow];
    const bool diag = (rowBase == colBase);

    // half 0 MFMA -> accA; previous tile's half-1 mining (accB) overlaps it
    halfMFMA(accA, 0);
    if (ct > 0) mineTile(accB, clbP[2], clbP[3], 32 + lrow, 48 + lrow, diagP);

    // half 1 MFMA -> accB; this tile's half-0 mining (accA) overlaps it
    halfMFMA(accB, 2);
    mineTile(accA, clb[0], clb[1], 0 + lrow, 16 + lrow, diag);

    __syncthreads();   // drains staging vmcnt + publishes buf^1, protects reuse
    #pragma unroll
    for (int ni = 0; ni < 4; ++ni) clbP[ni] = clb[ni];
    diagP = diag;
    cur ^= 1;
  }
  // pipeline drain: last tile's half 1
  mineTile(accB, clbP[2], clbP[3], 32 + lrow, 48 + lrow, diagP);

  // butterfly-reduce across the 16 lrow lanes sharing each C row, write partials
  const int part = blockIdx.y * 2 + wc;
  #pragma unroll
  for (int mi = 0; mi < 4; ++mi)
    #pragma unroll
    for (int r = 0; r < 4; ++r) {
      int p = ap[mi][r], n = an[mi][r];
      #pragma unroll
      for (int off = 1; off < 16; off <<= 1) {
        p = min(p, __shfl_xor(p, off));
        n = max(n, __shfl_xor(n, off));
      }
      if (lrow == 0) {
        int rg = rowBase + mi * 16 + lkg * 4 + r;
        ap_part[part * BN + rg] = p;
        an_part[part * BN + rg] = n;
      }
    }
}

// ---------------- K3a: per-row combine, d = sqrt(rs + 1 - 2*dot/127^2), margin ----------------
__global__ __launch_bounds__(256) void finalize_a_k(
    const int* __restrict__ ap_part, const int* __restrict__ an_part,
    const float* __restrict__ sqv,
    float* __restrict__ blk_sum, float* __restrict__ blk_cnt)
{
  int r = blockIdx.x * 256 + threadIdx.x;   // FBLK*256 == BN
  int apt = IMAX, ant = IMIN;               // min-idot pos / max-idot neg
  #pragma unroll 8
  for (int s = 0; s < NPART; ++s) {
    apt = min(apt, ap_part[s * BN + r]);
    ant = max(ant, an_part[s * BN + r]);
  }
  float sum = 0.f, cnt = 0.f;
  if (apt != IMAX && ant != IMIN) {
    const float sc = 2.0f / (127.0f * 127.0f);
    float rs1 = sqv[r] + 1.0f;
    float dap = sqrtf(fmaxf(fmaf(-sc, (float)apt, rs1), 0.f));
    float dan = sqrtf(fmaxf(fmaf(-sc, (float)ant, rs1), 0.f));
    sum = fmaxf(dap - dan + MARGIN_F, 0.f);
    cnt = 1.f;
  }
  #pragma unroll
  for (int off = 32; off > 0; off >>= 1) {
    sum += __shfl_xor(sum, off);
    cnt += __shfl_xor(cnt, off);
  }
  __shared__ float ssum[4], scnt[4];
  int wv = threadIdx.x >> 6;
  if ((threadIdx.x & 63) == 0) { ssum[wv] = sum; scnt[wv] = cnt; }
  __syncthreads();
  if (threadIdx.x == 0) {
    blk_sum[blockIdx.x] = ssum[0] + ssum[1] + ssum[2] + ssum[3];
    blk_cnt[blockIdx.x] = scnt[0] + scnt[1] + scnt[2] + scnt[3];
  }
}

// ---------------- K3b: final scalar ----------------
__global__ __launch_bounds__(64) void finalize_b_k(
    const float* __restrict__ blk_sum, const float* __restrict__ blk_cnt,
    float* __restrict__ out)
{
  int l = threadIdx.x;
  float s = (l < FBLK) ? blk_sum[l] : 0.f;
  float c = (l < FBLK) ? blk_cnt[l] : 0.f;
  #pragma unroll
  for (int off = 32; off > 0; off >>= 1) {
    s += __shfl_xor(s, off);
    c += __shfl_xor(c, off);
  }
  if (l == 0) out[0] = (c > 0.f) ? (s / c) : 0.f;
}

extern "C" void kernel_launch(void* const* d_in, const int* in_sizes, int n_in,
                              void* d_out, int out_size, void* d_ws, size_t ws_size,
                              hipStream_t stream)
{
  const float* emb = (const float*)d_in[0];
  const int*   lab = (const int*)d_in[1];
  float* out = (float*)d_out;
  float* ws  = (float*)d_ws;

  float* sqv     = ws;                          // BN floats
  int*   ap_part = (int*)(sqv + BN);            // NPART*BN ints
  int*   an_part = ap_part + NPART * BN;        // NPART*BN ints
  float* blk_sum = (float*)(an_part + NPART * BN);  // FBLK
  float* blk_cnt = blk_sum + FBLK;              // FBLK
  char*  EnQ     = (char*)(blk_cnt + FBLK);     // BN*DIM i8, k-major (~1 MB)

  norm_cvt_k<<<dim3(BN / 4), 256, 0, stream>>>(emb, sqv, (unsigned short*)EnQ);
  gram_mine_mfma_k<<<dim3(BN / 128, NSPLIT), 256, 0, stream>>>(EnQ, lab, ap_part, an_part);
  finalize_a_k<<<dim3(FBLK), 256, 0, stream>>>(ap_part, an_part, sqv, blk_sum, blk_cnt);
  finalize_b_k<<<dim3(1), 64, 0, stream>>>(blk_sum, blk_cnt, out);
}

// Round 8
// 33.263 us; speedup vs baseline: 1.8740x; 1.0060x over previous
//
#include <hip/hip_runtime.h>
#include <cmath>

#define BN 8192
#define DIM 128
#define MARGIN_F 0.3f
#define NSPLIT 8            // column splits (1024 cols each)
#define CPS 1024
#define NT 8                // 128-col B tiles per panel
#define NPART (NSPLIT * 2)  // per-row partials: split x wc
#define FBLK 32
#define IMAX 0x7FFFFFFF
#define IMIN 0x80000000

typedef __attribute__((ext_vector_type(4))) int i32x4;

__device__ __forceinline__ int imin3(int a, int b, int c) { return min(a, min(b, c)); }
__device__ __forceinline__ int imax3(int a, int b, int c) { return max(a, max(b, c)); }

// ---------------- K1: fp32 row norms -> sqv + k-major i8 quantized copy ----------------
// Also builds LP: packed column-label table. LP[cb*16 + lrow] holds the 4 label bytes
// {lab[cb*64 + n*16 + lrow], n=0..3} so K2 reads ONE u32 per tile-half instead of 4
// scattered global loads (cb = 64-col group index, 128 groups -> 8 KB, L2-resident).
__global__ __launch_bounds__(256) void norm_cvt_k(
    const float* __restrict__ emb, const int* __restrict__ lab,
    float* __restrict__ sqv, unsigned short* __restrict__ EnQ16,
    unsigned* __restrict__ LP)
{
  int gt = blockIdx.x * blockDim.x + threadIdx.x;
  if (gt < 2048) {
    int base = (gt >> 4) * 64 + (gt & 15);
    LP[gt] = (unsigned)(lab[base] & 255) | ((unsigned)(lab[base + 16] & 255) << 8) |
             ((unsigned)(lab[base + 32] & 255) << 16) | ((unsigned)(lab[base + 48] & 255) << 24);
  }

  int w = gt >> 6;  // one wave per row
  int lane = threadIdx.x & 63;
  if (w >= BN) return;
  float2 v = *reinterpret_cast<const float2*>(&emb[w * DIM + lane * 2]);
  float s = v.x * v.x + v.y * v.y;
  #pragma unroll
  for (int off = 32; off > 0; off >>= 1) s += __shfl_xor(s, off);
  float iv = 1.0f / fmaxf(sqrtf(s), 1e-12f);
  if (lane == 0) sqv[w] = s * iv * iv;
  int q0 = (int)rintf(127.0f * v.x * iv);
  int q1 = (int)rintf(127.0f * v.y * iv);
  unsigned short us = (unsigned short)((q0 & 255) | ((q1 & 255) << 8));
  int g = lane >> 3;                                  // k = 2*lane -> chunk g = lane/8
  EnQ16[(g * BN + w) * 8 + (lane & 7)] = us;
}

// ---------------- K2: barrier-free i8-MFMA gram + hard mining ----------------
// r6 PMC: MfmaUtil 15.7%, VALUBusy 48%, ~36% stall; mining core is only ~4.3us of
// the 9.8us VALU -> rest was staging/label/address overhead, and the stall was the
// per-tile __syncthreads + vmcnt(0) drain. EnQ is 1 MB = L2-resident, so LDS
// staging buys nothing: read B-frags DIRECTLY from global (L1/L2 hits, 4x256B
// contiguous per wave-load), drop LDS + all barriers; waves run free. Half-deep
// pipeline from r7 retained (mine previous half under current half's MFMA+loads).
__global__ __launch_bounds__(256, 2) void gram_mine_mfma_k(
    const char* __restrict__ EnQ, const int* __restrict__ lab,
    const unsigned* __restrict__ LP,
    int* __restrict__ ap_part, int* __restrict__ an_part)
{
  const int tid = threadIdx.x;
  const int w = tid >> 6, l = tid & 63;
  const int wr = w >> 1, wc = w & 1;
  const int lrow = l & 15, lkg = l >> 4;

  const int rowBase = blockIdx.x * 128 + wr * 64;   // this wave's 64 rows
  const int panel   = blockIdx.y * CPS;

  // A fragments: 4 row-tiles x 2 K-steps (K=64 each), 16B per frag, coalesced
  i32x4 a[4][2];
  #pragma unroll
  for (int mi = 0; mi < 4; ++mi)
    #pragma unroll
    for (int kk = 0; kk < 2; ++kk)
      a[mi][kk] = *reinterpret_cast<const i32x4*>(
          EnQ + (((size_t)((kk << 2) + lkg) * BN + rowBase + mi * 16 + lrow) << 4));

  // row labels for the 16 rows this lane owns, pre-extracted (tile-invariant)
  int rlv[4][4];
  #pragma unroll
  for (int mi = 0; mi < 4; ++mi) {
    int rb = rowBase + mi * 16 + lkg * 4;
    #pragma unroll
    for (int r = 0; r < 4; ++r) rlv[mi][r] = lab[rb + r] & 255;
  }

  int ap[4][4], an[4][4];
  #pragma unroll
  for (int mi = 0; mi < 4; ++mi)
    #pragma unroll
    for (int r = 0; r < 4; ++r) { ap[mi][r] = IMAX; an[mi][r] = IMIN; }

  const i32x4 zf = {0, 0, 0, 0};   // shared zero C-operand

  // B pointers: two bases (kk=0,1), advanced 2048 B per 128-col tile; n offsets are
  // immediate (n*256). Address: ((kk*4+lkg)*BN + colTile + wc*64 + n*16 + lrow)*16.
  const int colLane = wc * 64 + lrow;
  const char* bp0 = EnQ + (((size_t)lkg * BN + panel + colLane) << 4);
  const char* bp1 = bp0 + ((size_t)BN << 6);   // += 4*BN*16

  auto loadHalf = [&](i32x4 (&b)[2][2], const char* p0, const char* p1, int n0) {
    #pragma unroll
    for (int n = 0; n < 2; ++n) {
      b[0][n] = *reinterpret_cast<const i32x4*>(p0 + (n0 + n) * 256);
      b[1][n] = *reinterpret_cast<const i32x4*>(p1 + (n0 + n) * 256);
    }
  };
  auto mfmaHalf = [&](i32x4 (&A)[4][2], const i32x4 (&b)[2][2]) {
    #pragma unroll
    for (int mi = 0; mi < 4; ++mi)
      #pragma unroll
      for (int n = 0; n < 2; ++n)
        A[mi][n] = __builtin_amdgcn_mfma_i32_16x16x64_i8(a[mi][0], b[0][n], zf, 0, 0, 0);
    #pragma unroll
    for (int mi = 0; mi < 4; ++mi)
      #pragma unroll
      for (int n = 0; n < 2; ++n)
        A[mi][n] = __builtin_amdgcn_mfma_i32_16x16x64_i8(a[mi][1], b[1][n], A[mi][n], 0, 0, 0);
  };

  // mine one 64x32 half: l0/l1 = column labels of the two 16-col subtiles (per-lane),
  // c0/c1 = local column index of this lane in those subtiles (self-exclusion on diag)
  auto mineTile = [&](const i32x4 (&A)[4][2], int l0, int l1, int c0, int c1, bool dg) {
    if (!dg) {
      #pragma unroll
      for (int mi = 0; mi < 4; ++mi)
        #pragma unroll
        for (int r = 0; r < 4; ++r) {
          int d0 = A[mi][0][r], d1 = A[mi][1][r];
          bool s0 = (rlv[mi][r] == l0), s1 = (rlv[mi][r] == l1);
          int p0 = s0 ? d0 : IMAX;
          int p1 = s1 ? d1 : IMAX;
          int q0 = s0 ? IMIN : d0;
          int q1 = s1 ? IMIN : d1;
          ap[mi][r] = imin3(ap[mi][r], p0, p1);
          an[mi][r] = imax3(an[mi][r], q0, q1);
        }
    } else {
      #pragma unroll
      for (int mi = 0; mi < 4; ++mi)
        #pragma unroll
        for (int r = 0; r < 4; ++r) {
          int rloc = mi * 16 + lkg * 4 + r;
          int d0 = A[mi][0][r], d1 = A[mi][1][r];
          bool s0 = (rlv[mi][r] == l0), s1 = (rlv[mi][r] == l1);
          bool e0 = (rloc == c0), e1 = (rloc == c1);
          int p0 = (s0 && !e0) ? d0 : IMAX;
          int p1 = (s1 && !e1) ? d1 : IMAX;
          int q0 = s0 ? IMIN : d0;
          int q1 = s1 ? IMIN : d1;
          ap[mi][r] = imin3(ap[mi][r], p0, p1);
          an[mi][r] = imax3(an[mi][r], q0, q1);
        }
    }
  };

  i32x4 accA[4][2], accB[4][2];
  i32x4 bA[2][2], bB[2][2];
  int lprev0 = 0, lprev1 = 0;
  bool diagP = false;

  loadHalf(bA, bp0, bp1, 0);   // tile 0, half 0

  #pragma unroll 1
  for (int ct = 0; ct < NT; ++ct) {
    const int colBase = panel + ct * 128 + wc * 64;
    const bool diag = (rowBase == colBase);

    // packed column labels for this wave's 64 cols: one u32
    const unsigned LPv = LP[(colBase >> 6) * 16 + lrow];
    const int l0 = (int)(LPv & 255u),         l1 = (int)((LPv >> 8) & 255u);
    const int l2 = (int)((LPv >> 16) & 255u), l3 = (int)(LPv >> 24);

    loadHalf(bB, bp0, bp1, 2);           // this tile, half 1 (in flight)
    mfmaHalf(accA, bA);                  // half 0 MFMA (waits on bA)
    if (ct > 0) mineTile(accB, lprev0, lprev1, 32 + lrow, 48 + lrow, diagP);  // prev half 1

    bp0 += 2048; bp1 += 2048;
    if (ct + 1 < NT) loadHalf(bA, bp0, bp1, 0);   // next tile, half 0 (in flight)

    mfmaHalf(accB, bB);                  // half 1 MFMA
    mineTile(accA, l0, l1, 0 + lrow, 16 + lrow, diag);   // this half 0

    lprev0 = l2; lprev1 = l3; diagP = diag;
  }
  // drain: last tile's half 1
  mineTile(accB, lprev0, lprev1, 32 + lrow, 48 + lrow, diagP);

  // butterfly-reduce across the 16 lrow lanes sharing each C row, write partials
  const int part = blockIdx.y * 2 + wc;
  #pragma unroll
  for (int mi = 0; mi < 4; ++mi)
    #pragma unroll
    for (int r = 0; r < 4; ++r) {
      int p = ap[mi][r], n = an[mi][r];
      #pragma unroll
      for (int off = 1; off < 16; off <<= 1) {
        p = min(p, __shfl_xor(p, off));
        n = max(n, __shfl_xor(n, off));
      }
      if (lrow == 0) {
        int rg = rowBase + mi * 16 + lkg * 4 + r;
        ap_part[part * BN + rg] = p;
        an_part[part * BN + rg] = n;
      }
    }
}

// ---------------- K3a: per-row combine, d = sqrt(rs + 1 - 2*dot/127^2), margin ----------------
__global__ __launch_bounds__(256) void finalize_a_k(
    const int* __restrict__ ap_part, const int* __restrict__ an_part,
    const float* __restrict__ sqv,
    float* __restrict__ blk_sum, float* __restrict__ blk_cnt)
{
  int r = blockIdx.x * 256 + threadIdx.x;   // FBLK*256 == BN
  int apt = IMAX, ant = IMIN;               // min-idot pos / max-idot neg
  #pragma unroll 8
  for (int s = 0; s < NPART; ++s) {
    apt = min(apt, ap_part[s * BN + r]);
    ant = max(ant, an_part[s * BN + r]);
  }
  float sum = 0.f, cnt = 0.f;
  if (apt != IMAX && ant != IMIN) {
    const float sc = 2.0f / (127.0f * 127.0f);
    float rs1 = sqv[r] + 1.0f;
    float dap = sqrtf(fmaxf(fmaf(-sc, (float)apt, rs1), 0.f));
    float dan = sqrtf(fmaxf(fmaf(-sc, (float)ant, rs1), 0.f));
    sum = fmaxf(dap - dan + MARGIN_F, 0.f);
    cnt = 1.f;
  }
  #pragma unroll
  for (int off = 32; off > 0; off >>= 1) {
    sum += __shfl_xor(sum, off);
    cnt += __shfl_xor(cnt, off);
  }
  __shared__ float ssum[4], scnt[4];
  int wv = threadIdx.x >> 6;
  if ((threadIdx.x & 63) == 0) { ssum[wv] = sum; scnt[wv] = cnt; }
  __syncthreads();
  if (threadIdx.x == 0) {
    blk_sum[blockIdx.x] = ssum[0] + ssum[1] + ssum[2] + ssum[3];
    blk_cnt[blockIdx.x] = scnt[0] + scnt[1] + scnt[2] + scnt[3];
  }
}

// ---------------- K3b: final scalar ----------------
__global__ __launch_bounds__(64) void finalize_b_k(
    const float* __restrict__ blk_sum, const float* __restrict__ blk_cnt,
    float* __restrict__ out)
{
  int l = threadIdx.x;
  float s = (l < FBLK) ? blk_sum[l] : 0.f;
  float c = (l < FBLK) ? blk_cnt[l] : 0.f;
  #pragma unroll
  for (int off = 32; off > 0; off >>= 1) {
    s += __shfl_xor(s, off);
    c += __shfl_xor(c, off);
  }
  if (l == 0) out[0] = (c > 0.f) ? (s / c) : 0.f;
}

extern "C" void kernel_launch(void* const* d_in, const int* in_sizes, int n_in,
                              void* d_out, int out_size, void* d_ws, size_t ws_size,
                              hipStream_t stream)
{
  const float* emb = (const float*)d_in[0];
  const int*   lab = (const int*)d_in[1];
  float* out = (float*)d_out;
  float* ws  = (float*)d_ws;

  float*    sqv     = ws;                          // BN floats
  int*      ap_part = (int*)(sqv + BN);            // NPART*BN ints
  int*      an_part = ap_part + NPART * BN;        // NPART*BN ints
  float*    blk_sum = (float*)(an_part + NPART * BN);  // FBLK
  float*    blk_cnt = blk_sum + FBLK;              // FBLK
  unsigned* LP      = (unsigned*)(blk_cnt + FBLK); // 2048 u32 (8 KB)
  char*     EnQ     = (char*)(LP + 2048);          // BN*DIM i8, k-major (~1 MB)

  norm_cvt_k<<<dim3(BN / 4), 256, 0, stream>>>(emb, lab, sqv, (unsigned short*)EnQ, LP);
  gram_mine_mfma_k<<<dim3(BN / 128, NSPLIT), 256, 0, stream>>>(EnQ, lab, LP, ap_part, an_part);
  finalize_a_k<<<dim3(FBLK), 256, 0, stream>>>(ap_part, an_part, sqv, blk_sum, blk_cnt);
  finalize_b_k<<<dim3(1), 64, 0, stream>>>(blk_sum, blk_cnt, out);
}